// Round 1
// baseline (683.139 us; speedup 1.0000x reference)
//
#include <hip/hip_runtime.h>
#include <math.h>

#define B_ 8
#define Q_ 100
#define T_ 50
#define HW_ 65536

// ---------------- legacy (atomic) fallback path constants ----------------
#define NSEG 64
#define SEG (HW_ / NSEG)    // 1024 K per block
#define NK32 (SEG / 32)     // 32 K-steps of 32
#define NSTR 52             // N stride in ws (50 t + ssum col + pad)

#define DSZ (B_ * Q_ * NSTR)       // 41600
#define WS_D1 0
#define WS_D2 DSZ
#define WS_SNEG (2 * DSZ)          // 800
#define WS_ST (2 * DSZ + B_ * Q_)  // 400
#define WS_TOTAL (2 * DSZ + B_ * Q_ + B_ * T_)

// ---------------- partial-store (atomic-free) path constants ----------------
#define PSEG 128
#define SEGP (HW_ / PSEG)          // 512 K per block
#define NK32P (SEGP / 32)          // 16 K-steps of 32
#define PROWS 101                  // 100 q rows + ones-row (gives st)
#define PCOLS 52                   // 50 t cols + ssum col (50) + sneg col (51)
#define PBLK ((size_t)B_ * PROWS * PCOLS)      // floats per seg per array
#define D2OFF ((size_t)PSEG * PBLK)            // float offset of D2 partials
#define WS_NEEDED_BYTES (2ull * D2OFF * 4ull)  // ~43 MB

typedef __attribute__((ext_vector_type(8))) short bf16x8;
typedef __attribute__((ext_vector_type(4))) float f32x4;

__device__ __forceinline__ unsigned short f2bf(float f) {
    union { float f; unsigned u; } v; v.f = f;
    unsigned r = v.u + 0x7FFF + ((v.u >> 16) & 1);
    return (unsigned short)(r >> 16);
}

// ======================= atomic-free main kernel =======================
// Grid (PSEG, B). Each block: all Q x T for one (b, K-segment), LDS-free,
// barrier-free, atomic-free. Row m==100 is an all-ones A-row so that
// D1[100][t] = sum_k t  (st) comes out of the MFMA for free. Column 50 of
// the B-frag is all-ones so D2[q][50] = sum_k sigmoid (ssum). sneg (softplus
// row sums) land in column 51. Partials reduced by finalize_p.
__global__ __launch_bounds__(256, 4) void gemm_fused_p(const float* __restrict__ pred,
                                                       const int* __restrict__ tgt,
                                                       float* __restrict__ ws) {
    const int seg = blockIdx.x;
    const int b   = blockIdx.y;
    const int tid = threadIdx.x;
    const int wave = tid >> 6;
    const int lane = tid & 63;
    const int quad = lane >> 4;
    const int l16  = lane & 15;

    // A (x) pointers: rows clamped into [0, Q_); row m==Q_ becomes the ones-row
    const float* xptr[2];
    int aones[2];
#pragma unroll
    for (int mt = 0; mt < 2; ++mt) {
        int m = (wave + mt * 4) * 16 + l16;
        aones[mt] = (m == Q_);
        int mr = m < Q_ ? m : Q_ - 1;
        xptr[mt] = pred + ((size_t)b * Q_ + mr) * HW_ + (size_t)seg * SEGP + quad * 8;
    }
    // B (t) pointers: rows clamped into [0, T_); col n==T_ is the ones column
    const int* tptr[4];
    short onesv[4];
#pragma unroll
    for (int nt = 0; nt < 4; ++nt) {
        int n = nt * 16 + l16;
        onesv[nt] = (n == T_) ? (short)0x3F80 : (short)0;
        int nr = n < T_ ? n : T_ - 1;
        tptr[nt] = tgt + ((size_t)b * T_ + nr) * HW_ + (size_t)seg * SEGP + quad * 8;
    }

    f32x4 accx[2][4], accs[2][4];
#pragma unroll
    for (int mt = 0; mt < 2; ++mt)
#pragma unroll
        for (int nt = 0; nt < 4; ++nt) {
            accx[mt][nt] = (f32x4)(0.f);
            accs[mt][nt] = (f32x4)(0.f);
        }
    float sneg[2] = {0.f, 0.f};

    float4 xrb[2][2][2];
    int4   trb[2][4][2];

    // t loaded first (consumed first in compute) so x loads stay in flight
    auto loadraw = [&](int ch, float4 xr[2][2], int4 tr[4][2]) {
        const int k = ch * 32;
#pragma unroll
        for (int nt = 0; nt < 4; ++nt) {
            tr[nt][0] = *(const int4*)(tptr[nt] + k);
            tr[nt][1] = *(const int4*)(tptr[nt] + k + 4);
        }
#pragma unroll
        for (int mt = 0; mt < 2; ++mt) {
            xr[mt][0] = *(const float4*)(xptr[mt] + k);
            xr[mt][1] = *(const float4*)(xptr[mt] + k + 4);
        }
    };

    auto compute = [&](float4 xr[2][2], int4 tr[4][2]) {
        bf16x8 tf[4];
#pragma unroll
        for (int nt = 0; nt < 4; ++nt)
#pragma unroll
            for (int h = 0; h < 2; ++h)
#pragma unroll
                for (int e = 0; e < 4; ++e) {
                    int v = (&tr[nt][h].x)[e];
                    tf[nt][h * 4 + e] = v ? (short)0x3F80 : onesv[nt];
                }
#pragma unroll
        for (int mt = 0; mt < 2; ++mt) {
            bf16x8 xf, sf;
            float sp = 0.f;
#pragma unroll
            for (int h = 0; h < 2; ++h)
#pragma unroll
                for (int e = 0; e < 4; ++e) {
                    float x = (&xr[mt][h].x)[e];
                    float ax = fabsf(x);
                    float ee = __expf(-ax);
                    float d = 1.f + ee;
                    float r1 = __builtin_amdgcn_rcpf(d);
                    float sg = (x >= 0.f) ? r1 : ee * r1;              // sigmoid
                    sp += fmaxf(x, 0.f) + 0.69314718056f * __log2f(d); // softplus
                    xf[h * 4 + e] = aones[mt] ? (short)0x3F80 : (short)f2bf(x);
                    sf[h * 4 + e] = aones[mt] ? (short)0x3F80 : (short)f2bf(sg);
                }
            sneg[mt] += sp;
#pragma unroll
            for (int nt = 0; nt < 4; ++nt) {
                accx[mt][nt] = __builtin_amdgcn_mfma_f32_16x16x32_bf16(xf, tf[nt], accx[mt][nt], 0, 0, 0);
                accs[mt][nt] = __builtin_amdgcn_mfma_f32_16x16x32_bf16(sf, tf[nt], accs[mt][nt], 0, 0, 0);
            }
        }
    };

    loadraw(0, xrb[0], trb[0]);
#pragma unroll 2
    for (int ch = 0; ch < NK32P; ++ch) {
        const int cb = ch & 1;
        if (ch + 1 < NK32P) loadraw(ch + 1, xrb[cb ^ 1], trb[cb ^ 1]);
        compute(xrb[cb], trb[cb]);
    }

    // ---- epilogue: plain coalesced partial stores, zero atomics ----
    float* d1 = ws + (size_t)(seg * B_ + b) * ((size_t)PROWS * PCOLS);
    float* d2 = d1 + D2OFF;

    // softplus row sums -> column 51 of this block's D1 partial
#pragma unroll
    for (int mt = 0; mt < 2; ++mt) {
        float v = sneg[mt];
        v += __shfl_xor(v, 16);
        v += __shfl_xor(v, 32);
        int m = (wave + mt * 4) * 16 + l16;
        if (quad == 0 && m < Q_) d1[(size_t)m * PCOLS + 51] = v;
    }
    // D partials; C/D layout: col = l16 (n), row-within-tile = quad*4 + r
#pragma unroll
    for (int mt = 0; mt < 2; ++mt) {
        int mtile = (wave + mt * 4) * 16;
#pragma unroll
        for (int nt = 0; nt < 4; ++nt) {
            int n = nt * 16 + l16;
#pragma unroll
            for (int r = 0; r < 4; ++r) {
                int m = mtile + quad * 4 + r;
                if (m <= Q_ && n <= T_) {   // includes ones-row (st) and ssum col
                    size_t idx = (size_t)m * PCOLS + n;
                    d1[idx] = accx[mt][nt][r];
                    d2[idx] = accs[mt][nt][r];
                }
            }
        }
    }
}

__global__ void finalize_p(const float* __restrict__ ws, float* __restrict__ out) {
    int i = blockIdx.x * blockDim.x + threadIdx.x;
    if (i >= B_ * Q_ * T_) return;
    int b = i / (Q_ * T_);
    int r = i % (Q_ * T_);
    int q = r / T_;
    int t = r % T_;
    const float* d1 = ws;
    const float* d2 = ws + D2OFF;
    size_t offq = ((size_t)b * PROWS + q) * PCOLS;
    size_t offo = ((size_t)b * PROWS + Q_) * PCOLS;  // ones-row (st)
    float dx = 0.f, ds = 0.f, ss = 0.f, sn = 0.f, stv = 0.f;
#pragma unroll 4
    for (int s = 0; s < PSEG; ++s) {
        size_t base = (size_t)s * PBLK;
        dx  += d1[base + offq + t];
        ds  += d2[base + offq + t];
        ss  += d2[base + offq + T_];
        sn  += d1[base + offq + 51];
        stv += d1[base + offo + t];
    }
    float ce = (sn - dx) * (1.f / (float)HW_);
    float dice = 1.f - (2.f * ds + 1.f) / (ss + stv + 1.f);
    out[i] = ce + dice;
}

// ======================= legacy atomic fallback (verbatim) =======================
__global__ void zero_ws(float* ws) {
    int i = blockIdx.x * blockDim.x + threadIdx.x;
    if (i < WS_TOTAL) ws[i] = 0.f;
}

__global__ __launch_bounds__(256, 2) void gemm_fused(const float* __restrict__ pred,
                                                     const int* __restrict__ tgt,
                                                     float* __restrict__ ws) {
    const int seg = blockIdx.x;
    const int b   = blockIdx.y;
    const int tid = threadIdx.x;
    const int wave = tid >> 6;
    const int lane = tid & 63;
    const int quad = lane >> 4;
    const int l16  = lane & 15;

    const float* xptr[2];
#pragma unroll
    for (int mt = 0; mt < 2; ++mt) {
        int m = (wave + mt * 4) * 16 + l16;
        int mr = m < Q_ ? m : Q_ - 1;
        xptr[mt] = pred + ((size_t)b * Q_ + mr) * HW_ + (size_t)seg * SEG + quad * 8;
    }
    const int* tptr[4];
    int ones[4];
#pragma unroll
    for (int nt = 0; nt < 4; ++nt) {
        int n = nt * 16 + l16;
        ones[nt] = (n == T_);
        int nr = n < T_ ? n : T_ - 1;
        tptr[nt] = tgt + ((size_t)b * T_ + nr) * HW_ + (size_t)seg * SEG + quad * 8;
    }

    f32x4 accx[2][4], accs[2][4];
#pragma unroll
    for (int mt = 0; mt < 2; ++mt)
#pragma unroll
        for (int nt = 0; nt < 4; ++nt) {
            accx[mt][nt] = (f32x4)(0.f);
            accs[mt][nt] = (f32x4)(0.f);
        }
    float sneg[2] = {0.f, 0.f};
    float stq[4] = {0.f, 0.f, 0.f, 0.f};

    float4 xrb[2][2][2];
    int4   trb[2][4][2];

    auto loadraw = [&](int ch, float4 xr[2][2], int4 tr[4][2]) {
        const int k = ch * 32;
#pragma unroll
        for (int mt = 0; mt < 2; ++mt) {
            xr[mt][0] = *(const float4*)(xptr[mt] + k);
            xr[mt][1] = *(const float4*)(xptr[mt] + k + 4);
        }
#pragma unroll
        for (int nt = 0; nt < 4; ++nt) {
            tr[nt][0] = *(const int4*)(tptr[nt] + k);
            tr[nt][1] = *(const int4*)(tptr[nt] + k + 4);
        }
    };

    auto compute = [&](float4 xr[2][2], int4 tr[4][2]) {
        bf16x8 tf[4];
#pragma unroll
        for (int nt = 0; nt < 4; ++nt) {
            float cnt = 0.f;
#pragma unroll
            for (int h = 0; h < 2; ++h)
#pragma unroll
                for (int e = 0; e < 4; ++e) {
                    int v = (&tr[nt][h].x)[e];
                    tf[nt][h * 4 + e] = (v || ones[nt]) ? (short)0x3F80 : (short)0;
                    cnt += v ? 1.f : 0.f;
                }
            stq[nt] += cnt;
        }
#pragma unroll
        for (int mt = 0; mt < 2; ++mt) {
            bf16x8 xf, sf;
            float sp = 0.f;
#pragma unroll
            for (int h = 0; h < 2; ++h)
#pragma unroll
                for (int e = 0; e < 4; ++e) {
                    float x = (&xr[mt][h].x)[e];
                    float ax = fabsf(x);
                    float ee = __expf(-ax);
                    float d = 1.f + ee;
                    float r1 = __builtin_amdgcn_rcpf(d);
                    float sg = (x >= 0.f) ? r1 : ee * r1;
                    sp += fmaxf(x, 0.f) + 0.69314718056f * __log2f(d);
                    xf[h * 4 + e] = (short)f2bf(x);
                    sf[h * 4 + e] = (short)f2bf(sg);
                }
            sneg[mt] += sp;
#pragma unroll
            for (int nt = 0; nt < 4; ++nt) {
                accx[mt][nt] = __builtin_amdgcn_mfma_f32_16x16x32_bf16(xf, tf[nt], accx[mt][nt], 0, 0, 0);
                accs[mt][nt] = __builtin_amdgcn_mfma_f32_16x16x32_bf16(sf, tf[nt], accs[mt][nt], 0, 0, 0);
            }
        }
    };

    loadraw(0, xrb[0], trb[0]);
#pragma unroll 2
    for (int ch = 0; ch < NK32; ++ch) {
        const int cb = ch & 1;
        if (ch + 1 < NK32) loadraw(ch + 1, xrb[cb ^ 1], trb[cb ^ 1]);
        compute(xrb[cb], trb[cb]);
    }

#pragma unroll
    for (int mt = 0; mt < 2; ++mt) {
        float v = sneg[mt];
        v += __shfl_xor(v, 16);
        v += __shfl_xor(v, 32);
        int m = (wave + mt * 4) * 16 + l16;
        if (quad == 0 && m < Q_) atomicAdd(&ws[WS_SNEG + b * Q_ + m], v);
    }
    if (wave == 0) {
#pragma unroll
        for (int nt = 0; nt < 4; ++nt) {
            float v = stq[nt];
            v += __shfl_xor(v, 16);
            v += __shfl_xor(v, 32);
            int n = nt * 16 + l16;
            if (quad == 0 && n < T_) atomicAdd(&ws[WS_ST + b * T_ + n], v);
        }
    }
#pragma unroll
    for (int mt = 0; mt < 2; ++mt) {
        int mtile = (wave + mt * 4) * 16;
#pragma unroll
        for (int nt = 0; nt < 4; ++nt) {
            int n = nt * 16 + l16;
#pragma unroll
            for (int r = 0; r < 4; ++r) {
                int m = mtile + quad * 4 + r;
                if (m < Q_) {
                    size_t idx = ((size_t)b * Q_ + m) * NSTR + n;
                    if (n < T_) atomicAdd(&ws[WS_D1 + idx], accx[mt][nt][r]);
                    if (n <= T_) atomicAdd(&ws[WS_D2 + idx], accs[mt][nt][r]);
                }
            }
        }
    }
}

__global__ void finalize(const float* __restrict__ ws, float* __restrict__ out) {
    int i = blockIdx.x * blockDim.x + threadIdx.x;
    if (i >= B_ * Q_ * T_) return;
    int b = i / (Q_ * T_);
    int r = i % (Q_ * T_);
    int q = r / T_;
    int t = r % T_;
    float dx   = ws[WS_D1 + ((size_t)b * Q_ + q) * NSTR + t];
    float ds   = ws[WS_D2 + ((size_t)b * Q_ + q) * NSTR + t];
    float ssum = ws[WS_D2 + ((size_t)b * Q_ + q) * NSTR + T_];
    float st   = ws[WS_ST + b * T_ + t];
    float sneg = ws[WS_SNEG + b * Q_ + q];
    float ce = (sneg - dx) * (1.f / (float)HW_);
    float dice = 1.f - (2.f * ds + 1.f) / (ssum + st + 1.f);
    out[i] = ce + dice;
}

extern "C" void kernel_launch(void* const* d_in, const int* in_sizes, int n_in,
                              void* d_out, int out_size, void* d_ws, size_t ws_size,
                              hipStream_t stream) {
    const float* pred = (const float*)d_in[0];
    const int* tgt = (const int*)d_in[1];
    float* ws = (float*)d_ws;
    float* out = (float*)d_out;

    if (ws_size >= WS_NEEDED_BYTES) {
        // atomic-free path: 1024 blocks (4/CU, 16 waves/CU), partial stores + reduce
        dim3 g(PSEG, B_, 1);
        gemm_fused_p<<<g, 256, 0, stream>>>(pred, tgt, ws);
        finalize_p<<<(B_ * Q_ * T_ + 255) / 256, 256, 0, stream>>>(ws, out);
    } else {
        // legacy atomic path
        zero_ws<<<(WS_TOTAL + 255) / 256, 256, 0, stream>>>(ws);
        dim3 g(NSEG, B_, 1);
        gemm_fused<<<g, 256, 0, stream>>>(pred, tgt, ws);
        finalize<<<(B_ * Q_ * T_ + 255) / 256, 256, 0, stream>>>(ws, out);
    }
}

// Round 2
// 382.294 us; speedup vs baseline: 1.7869x; 1.7869x over previous
//
#include <hip/hip_runtime.h>
#include <math.h>

#define B_ 8
#define Q_ 100
#define T_ 50
#define HW_ 65536

// ---------------- legacy (atomic) fallback path constants ----------------
#define NSEG 64
#define SEG (HW_ / NSEG)    // 1024 K per block
#define NK32 (SEG / 32)     // 32 K-steps of 32
#define NSTR 52             // N stride in ws (50 t + ssum col + pad)

#define DSZ (B_ * Q_ * NSTR)       // 41600
#define WS_D1 0
#define WS_D2 DSZ
#define WS_SNEG (2 * DSZ)          // 800
#define WS_ST (2 * DSZ + B_ * Q_)  // 400
#define WS_TOTAL (2 * DSZ + B_ * Q_ + B_ * T_)

// ---------------- partial-store (atomic-free) path constants ----------------
// Same grid/main-loop as the proven 172us kernel; only the epilogue differs.
#define PSEG 64
#define SEGP (HW_ / PSEG)          // 1024 K per block
#define NK32P (SEGP / 32)          // 32 K-steps of 32
#define PROWS 101                  // 100 q rows + ones-row (gives st)
#define PCOLS 52                   // 50 t cols + ssum col (50) + sneg col (51)
#define PTILE ((size_t)PROWS * PCOLS)          // 5252 floats per (seg,b) per array
#define PBLK ((size_t)B_ * PTILE)              // 42016 floats per seg per array
#define D2OFF ((size_t)PSEG * PBLK)            // float offset of D2 partials
#define WS_NEEDED_BYTES (2ull * D2OFF * 4ull)  // ~21.5 MB

typedef __attribute__((ext_vector_type(8))) short bf16x8;
typedef __attribute__((ext_vector_type(4))) float f32x4;

__device__ __forceinline__ unsigned short f2bf(float f) {
    union { float f; unsigned u; } v; v.f = f;
    unsigned r = v.u + 0x7FFF + ((v.u >> 16) & 1);
    return (unsigned short)(r >> 16);
}

// ======================= atomic-free main kernel =======================
// Grid (PSEG, B). Each block: all Q x T for one (b, K-segment), LDS-free,
// barrier-free, atomic-free. Row m==100 is an all-ones A-row so that
// D1[100][t] = sum_k t  (st) comes out of the MFMA for free. Column n==50
// of the B-frag is all-ones so D2[q][50] = sum_k sigmoid (ssum). sneg
// (softplus row sums) land in column 51. Partials reduced by finalize_p.
// NOTE: __launch_bounds__(256,2) — (256,4) forced VGPR 120->64 and 1.4 GB
// of scratch spill traffic (round-1 regression). Keep the allocator free.
__global__ __launch_bounds__(256, 2) void gemm_fused_p(const float* __restrict__ pred,
                                                       const int* __restrict__ tgt,
                                                       float* __restrict__ ws) {
    const int seg = blockIdx.x;
    const int b   = blockIdx.y;
    const int tid = threadIdx.x;
    const int wave = tid >> 6;
    const int lane = tid & 63;
    const int quad = lane >> 4;
    const int l16  = lane & 15;

    // A (x) pointers: rows clamped into [0, Q_); row m==Q_ becomes the ones-row
    const float* xptr[2];
    int aones[2];
#pragma unroll
    for (int mt = 0; mt < 2; ++mt) {
        int m = (wave + mt * 4) * 16 + l16;
        aones[mt] = (m == Q_);
        int mr = m < Q_ ? m : Q_ - 1;
        xptr[mt] = pred + ((size_t)b * Q_ + mr) * HW_ + (size_t)seg * SEGP + quad * 8;
    }
    // B (t) pointers: rows clamped into [0, T_); col n==T_ is the ones column
    const int* tptr[4];
    short onesv[4];
#pragma unroll
    for (int nt = 0; nt < 4; ++nt) {
        int n = nt * 16 + l16;
        onesv[nt] = (n == T_) ? (short)0x3F80 : (short)0;
        int nr = n < T_ ? n : T_ - 1;
        tptr[nt] = tgt + ((size_t)b * T_ + nr) * HW_ + (size_t)seg * SEGP + quad * 8;
    }

    f32x4 accx[2][4], accs[2][4];
#pragma unroll
    for (int mt = 0; mt < 2; ++mt)
#pragma unroll
        for (int nt = 0; nt < 4; ++nt) {
            accx[mt][nt] = (f32x4)(0.f);
            accs[mt][nt] = (f32x4)(0.f);
        }
    float sneg[2] = {0.f, 0.f};

    float4 xrb[2][2][2];
    int4   trb[2][4][2];

    auto loadraw = [&](int ch, float4 xr[2][2], int4 tr[4][2]) {
        const int k = ch * 32;
#pragma unroll
        for (int mt = 0; mt < 2; ++mt) {
            xr[mt][0] = *(const float4*)(xptr[mt] + k);
            xr[mt][1] = *(const float4*)(xptr[mt] + k + 4);
        }
#pragma unroll
        for (int nt = 0; nt < 4; ++nt) {
            tr[nt][0] = *(const int4*)(tptr[nt] + k);
            tr[nt][1] = *(const int4*)(tptr[nt] + k + 4);
        }
    };

    auto compute = [&](float4 xr[2][2], int4 tr[4][2]) {
        bf16x8 tf[4];
#pragma unroll
        for (int nt = 0; nt < 4; ++nt)
#pragma unroll
            for (int h = 0; h < 2; ++h)
#pragma unroll
                for (int e = 0; e < 4; ++e) {
                    int v = (&tr[nt][h].x)[e];
                    tf[nt][h * 4 + e] = v ? (short)0x3F80 : onesv[nt];
                }
#pragma unroll
        for (int mt = 0; mt < 2; ++mt) {
            bf16x8 xf, sf;
            float sp = 0.f;
#pragma unroll
            for (int h = 0; h < 2; ++h)
#pragma unroll
                for (int e = 0; e < 4; ++e) {
                    float x = (&xr[mt][h].x)[e];
                    float ax = fabsf(x);
                    float ee = __expf(-ax);
                    float d = 1.f + ee;
                    float r1 = __builtin_amdgcn_rcpf(d);
                    float sg = (x >= 0.f) ? r1 : ee * r1;              // sigmoid
                    sp += fmaxf(x, 0.f) + 0.69314718056f * __log2f(d); // softplus
                    xf[h * 4 + e] = aones[mt] ? (short)0x3F80 : (short)f2bf(x);
                    sf[h * 4 + e] = aones[mt] ? (short)0x3F80 : (short)f2bf(sg);
                }
            sneg[mt] += sp;
#pragma unroll
            for (int nt = 0; nt < 4; ++nt) {
                accx[mt][nt] = __builtin_amdgcn_mfma_f32_16x16x32_bf16(xf, tf[nt], accx[mt][nt], 0, 0, 0);
                accs[mt][nt] = __builtin_amdgcn_mfma_f32_16x16x32_bf16(sf, tf[nt], accs[mt][nt], 0, 0, 0);
            }
        }
    };

    loadraw(0, xrb[0], trb[0]);
#pragma unroll 2
    for (int ch = 0; ch < NK32P; ++ch) {
        const int cb = ch & 1;
        if (ch + 1 < NK32P) loadraw(ch + 1, xrb[cb ^ 1], trb[cb ^ 1]);
        compute(xrb[cb], trb[cb]);
    }

    // ---- epilogue: plain coalesced partial stores, zero atomics ----
    float* d1 = ws + (size_t)(seg * B_ + b) * PTILE;
    float* d2 = d1 + D2OFF;

    // softplus row sums -> column 51 of this block's D1 partial
#pragma unroll
    for (int mt = 0; mt < 2; ++mt) {
        float v = sneg[mt];
        v += __shfl_xor(v, 16);
        v += __shfl_xor(v, 32);
        int m = (wave + mt * 4) * 16 + l16;
        if (quad == 0 && m < Q_) d1[(size_t)m * PCOLS + 51] = v;
    }
    // D partials; C/D layout: col = l16 (n), row-within-tile = quad*4 + r
#pragma unroll
    for (int mt = 0; mt < 2; ++mt) {
        int mtile = (wave + mt * 4) * 16;
#pragma unroll
        for (int nt = 0; nt < 4; ++nt) {
            int n = nt * 16 + l16;
#pragma unroll
            for (int r = 0; r < 4; ++r) {
                int m = mtile + quad * 4 + r;
                if (m <= Q_ && n <= T_) {   // includes ones-row (st) and ssum col
                    size_t idx = (size_t)m * PCOLS + n;
                    d1[idx] = accx[mt][nt][r];
                    d2[idx] = accs[mt][nt][r];
                }
            }
        }
    }
}

__global__ void finalize_p(const float* __restrict__ ws, float* __restrict__ out) {
    int i = blockIdx.x * blockDim.x + threadIdx.x;
    if (i >= B_ * Q_ * T_) return;
    int b = i / (Q_ * T_);
    int r = i % (Q_ * T_);
    int q = r / T_;
    int t = r % T_;
    const float* d1 = ws;
    const float* d2 = ws + D2OFF;
    size_t offq = ((size_t)b * PROWS + q) * PCOLS;
    size_t offo = ((size_t)b * PROWS + Q_) * PCOLS;  // ones-row (st)
    float dx = 0.f, ds = 0.f, ss = 0.f, sn = 0.f, stv = 0.f;
#pragma unroll 4
    for (int s = 0; s < PSEG; ++s) {
        size_t base = (size_t)s * PBLK + (size_t)b * PTILE;
        dx  += d1[base + (size_t)q * PCOLS + t];
        ds  += d2[base + (size_t)q * PCOLS + t];
        ss  += d2[base + (size_t)q * PCOLS + T_];
        sn  += d1[base + (size_t)q * PCOLS + 51];
        stv += d1[base + (size_t)Q_ * PCOLS + t];
    }
    (void)offq; (void)offo;
    float ce = (sn - dx) * (1.f / (float)HW_);
    float dice = 1.f - (2.f * ds + 1.f) / (ss + stv + 1.f);
    out[i] = ce + dice;
}

// ======================= legacy atomic fallback (verbatim) =======================
__global__ void zero_ws(float* ws) {
    int i = blockIdx.x * blockDim.x + threadIdx.x;
    if (i < WS_TOTAL) ws[i] = 0.f;
}

__global__ __launch_bounds__(256, 2) void gemm_fused(const float* __restrict__ pred,
                                                     const int* __restrict__ tgt,
                                                     float* __restrict__ ws) {
    const int seg = blockIdx.x;
    const int b   = blockIdx.y;
    const int tid = threadIdx.x;
    const int wave = tid >> 6;
    const int lane = tid & 63;
    const int quad = lane >> 4;
    const int l16  = lane & 15;

    const float* xptr[2];
#pragma unroll
    for (int mt = 0; mt < 2; ++mt) {
        int m = (wave + mt * 4) * 16 + l16;
        int mr = m < Q_ ? m : Q_ - 1;
        xptr[mt] = pred + ((size_t)b * Q_ + mr) * HW_ + (size_t)seg * SEG + quad * 8;
    }
    const int* tptr[4];
    int ones[4];
#pragma unroll
    for (int nt = 0; nt < 4; ++nt) {
        int n = nt * 16 + l16;
        ones[nt] = (n == T_);
        int nr = n < T_ ? n : T_ - 1;
        tptr[nt] = tgt + ((size_t)b * T_ + nr) * HW_ + (size_t)seg * SEG + quad * 8;
    }

    f32x4 accx[2][4], accs[2][4];
#pragma unroll
    for (int mt = 0; mt < 2; ++mt)
#pragma unroll
        for (int nt = 0; nt < 4; ++nt) {
            accx[mt][nt] = (f32x4)(0.f);
            accs[mt][nt] = (f32x4)(0.f);
        }
    float sneg[2] = {0.f, 0.f};
    float stq[4] = {0.f, 0.f, 0.f, 0.f};

    float4 xrb[2][2][2];
    int4   trb[2][4][2];

    auto loadraw = [&](int ch, float4 xr[2][2], int4 tr[4][2]) {
        const int k = ch * 32;
#pragma unroll
        for (int mt = 0; mt < 2; ++mt) {
            xr[mt][0] = *(const float4*)(xptr[mt] + k);
            xr[mt][1] = *(const float4*)(xptr[mt] + k + 4);
        }
#pragma unroll
        for (int nt = 0; nt < 4; ++nt) {
            tr[nt][0] = *(const int4*)(tptr[nt] + k);
            tr[nt][1] = *(const int4*)(tptr[nt] + k + 4);
        }
    };

    auto compute = [&](float4 xr[2][2], int4 tr[4][2]) {
        bf16x8 tf[4];
#pragma unroll
        for (int nt = 0; nt < 4; ++nt) {
            float cnt = 0.f;
#pragma unroll
            for (int h = 0; h < 2; ++h)
#pragma unroll
                for (int e = 0; e < 4; ++e) {
                    int v = (&tr[nt][h].x)[e];
                    tf[nt][h * 4 + e] = (v || ones[nt]) ? (short)0x3F80 : (short)0;
                    cnt += v ? 1.f : 0.f;
                }
            stq[nt] += cnt;
        }
#pragma unroll
        for (int mt = 0; mt < 2; ++mt) {
            bf16x8 xf, sf;
            float sp = 0.f;
#pragma unroll
            for (int h = 0; h < 2; ++h)
#pragma unroll
                for (int e = 0; e < 4; ++e) {
                    float x = (&xr[mt][h].x)[e];
                    float ax = fabsf(x);
                    float ee = __expf(-ax);
                    float d = 1.f + ee;
                    float r1 = __builtin_amdgcn_rcpf(d);
                    float sg = (x >= 0.f) ? r1 : ee * r1;
                    sp += fmaxf(x, 0.f) + 0.69314718056f * __log2f(d);
                    xf[h * 4 + e] = (short)f2bf(x);
                    sf[h * 4 + e] = (short)f2bf(sg);
                }
            sneg[mt] += sp;
#pragma unroll
            for (int nt = 0; nt < 4; ++nt) {
                accx[mt][nt] = __builtin_amdgcn_mfma_f32_16x16x32_bf16(xf, tf[nt], accx[mt][nt], 0, 0, 0);
                accs[mt][nt] = __builtin_amdgcn_mfma_f32_16x16x32_bf16(sf, tf[nt], accs[mt][nt], 0, 0, 0);
            }
        }
    };

    loadraw(0, xrb[0], trb[0]);
#pragma unroll 2
    for (int ch = 0; ch < NK32; ++ch) {
        const int cb = ch & 1;
        if (ch + 1 < NK32) loadraw(ch + 1, xrb[cb ^ 1], trb[cb ^ 1]);
        compute(xrb[cb], trb[cb]);
    }

#pragma unroll
    for (int mt = 0; mt < 2; ++mt) {
        float v = sneg[mt];
        v += __shfl_xor(v, 16);
        v += __shfl_xor(v, 32);
        int m = (wave + mt * 4) * 16 + l16;
        if (quad == 0 && m < Q_) atomicAdd(&ws[WS_SNEG + b * Q_ + m], v);
    }
    if (wave == 0) {
#pragma unroll
        for (int nt = 0; nt < 4; ++nt) {
            float v = stq[nt];
            v += __shfl_xor(v, 16);
            v += __shfl_xor(v, 32);
            int n = nt * 16 + l16;
            if (quad == 0 && n < T_) atomicAdd(&ws[WS_ST + b * T_ + n], v);
        }
    }
#pragma unroll
    for (int mt = 0; mt < 2; ++mt) {
        int mtile = (wave + mt * 4) * 16;
#pragma unroll
        for (int nt = 0; nt < 4; ++nt) {
            int n = nt * 16 + l16;
#pragma unroll
            for (int r = 0; r < 4; ++r) {
                int m = mtile + quad * 4 + r;
                if (m < Q_) {
                    size_t idx = ((size_t)b * Q_ + m) * NSTR + n;
                    if (n < T_) atomicAdd(&ws[WS_D1 + idx], accx[mt][nt][r]);
                    if (n <= T_) atomicAdd(&ws[WS_D2 + idx], accs[mt][nt][r]);
                }
            }
        }
    }
}

__global__ void finalize(const float* __restrict__ ws, float* __restrict__ out) {
    int i = blockIdx.x * blockDim.x + threadIdx.x;
    if (i >= B_ * Q_ * T_) return;
    int b = i / (Q_ * T_);
    int r = i % (Q_ * T_);
    int q = r / T_;
    int t = r % T_;
    float dx   = ws[WS_D1 + ((size_t)b * Q_ + q) * NSTR + t];
    float ds   = ws[WS_D2 + ((size_t)b * Q_ + q) * NSTR + t];
    float ssum = ws[WS_D2 + ((size_t)b * Q_ + q) * NSTR + T_];
    float st   = ws[WS_ST + b * T_ + t];
    float sneg = ws[WS_SNEG + b * Q_ + q];
    float ce = (sneg - dx) * (1.f / (float)HW_);
    float dice = 1.f - (2.f * ds + 1.f) / (ssum + st + 1.f);
    out[i] = ce + dice;
}

extern "C" void kernel_launch(void* const* d_in, const int* in_sizes, int n_in,
                              void* d_out, int out_size, void* d_ws, size_t ws_size,
                              hipStream_t stream) {
    const float* pred = (const float*)d_in[0];
    const int* tgt = (const int*)d_in[1];
    float* ws = (float*)d_ws;
    float* out = (float*)d_out;

    if (ws_size >= WS_NEEDED_BYTES) {
        // atomic-free path: partial stores + segment reduction
        dim3 g(PSEG, B_, 1);
        gemm_fused_p<<<g, 256, 0, stream>>>(pred, tgt, ws);
        finalize_p<<<(B_ * Q_ * T_ + 255) / 256, 256, 0, stream>>>(ws, out);
    } else {
        // legacy atomic path
        zero_ws<<<(WS_TOTAL + 255) / 256, 256, 0, stream>>>(ws);
        dim3 g(NSEG, B_, 1);
        gemm_fused<<<g, 256, 0, stream>>>(pred, tgt, ws);
        finalize<<<(B_ * Q_ * T_ + 255) / 256, 256, 0, stream>>>(ws, out);
    }
}